// Round 7
// baseline (236.605 us; speedup 1.0000x reference)
//
#include <hip/hip_runtime.h>

typedef __bf16 bf16_t;
typedef __bf16 bf16x4 __attribute__((ext_vector_type(4)));
typedef __bf16 bf16x8 __attribute__((ext_vector_type(8)));
typedef float f32x4 __attribute__((ext_vector_type(4)));

#define N_PIX 4096
#define CFEAT 256
#define CKEY 32
#define NBATCH 4
#define LOG2E 1.4426950408889634f

static __device__ __forceinline__ f32x4 mfma16(bf16x8 a, bf16x8 b, f32x4 c) {
    return __builtin_amdgcn_mfma_f32_16x16x32_bf16(a, b, c, 0, 0, 0);
}
static __device__ __forceinline__ void glds16(const void* g, void* l) {
    __builtin_amdgcn_global_load_lds(
        (const __attribute__((address_space(1))) void*)g,
        (__attribute__((address_space(3))) void*)l, 16, 0, 0);
}
static __device__ __forceinline__ float fexp2(float x) {
#if __has_builtin(__builtin_amdgcn_exp2f)
    return __builtin_amdgcn_exp2f(x);   // v_exp_f32: D = 2^S0
#else
    return exp2f(x);
#endif
}

// ---------------------------------------------------------------------------
// wcvt: Wq*log2e, Wk, Wv -> bf16. 81920 elems, grid 320x256.
// ---------------------------------------------------------------------------
__global__ __launch_bounds__(256) void wcvt_kernel(
    const float* __restrict__ Wq, const float* __restrict__ Wk,
    const float* __restrict__ Wv,
    bf16_t* __restrict__ Wqb, bf16_t* __restrict__ Wkb, bf16_t* __restrict__ Wvb)
{
    const int i = blockIdx.x * 256 + threadIdx.x;
    if (i < 8192)        Wqb[i] = (bf16_t)(Wq[i] * LOG2E);
    else if (i < 16384)  Wkb[i - 8192] = (bf16_t)Wk[i - 8192];
    else                 Wvb[i - 16384] = (bf16_t)Wv[i - 16384];
}

// ---------------------------------------------------------------------------
// transpose: XT[b][n][c] = bf16(X[b][c][n]) for feat and cond.
// grid (N/64, C/64, 2*B), block 256.
// ---------------------------------------------------------------------------
__global__ __launch_bounds__(256) void transpose_kernel(
    const float* __restrict__ Xf, const float* __restrict__ Xc,
    bf16_t* __restrict__ XTf, bf16_t* __restrict__ XTc)
{
    __shared__ __attribute__((aligned(16))) bf16_t Ts[64][68];
    const int t = threadIdx.x;
    const int b = blockIdx.z & 3;
    const bool isC = blockIdx.z >= 4;
    const float* X  = (isC ? Xc : Xf) + (size_t)b * CFEAT * N_PIX;
    bf16_t*      XT = (isC ? XTc : XTf) + (size_t)b * N_PIX * CFEAT;
    const int c0 = blockIdx.y * 64, n0 = blockIdx.x * 64;

#pragma unroll
    for (int p = 0; p < 4; ++p) {
        const int c = (t >> 4) + p * 16;
        const int n = (t & 15) * 4;
        const f32x4 x = *(const f32x4*)&X[(size_t)(c0 + c) * N_PIX + n0 + n];
        bf16x4 v;
#pragma unroll
        for (int e = 0; e < 4; ++e) v[e] = (bf16_t)x[e];
        *(bf16x4*)&Ts[c][n] = v;
    }
    __syncthreads();
#pragma unroll
    for (int p = 0; p < 2; ++p) {
        const int n  = (t >> 3) + p * 32;
        const int cs = (t & 7) * 8;
        bf16x8 v;
#pragma unroll
        for (int e = 0; e < 8; ++e) v[e] = Ts[cs + e][n];
        *(bf16x8*)&XT[(size_t)(n0 + n) * CFEAT + c0 + cs] = v;
    }
}

// ---------------------------------------------------------------------------
// projqk: Qt[b][n][32] = log2e*(Wq.cond + bq) ; Kt = Wk.feat + bk.
// A = XT rows (16B), B = W^T from bf16 W rows (16B, hoisted).
// grid (N/32, B): waves 0,1 = Q n-tiles, waves 2,3 = K.
// ---------------------------------------------------------------------------
__global__ __launch_bounds__(256) void projqk_kernel(
    const bf16_t* __restrict__ Wqb, const float* __restrict__ bq,
    const bf16_t* __restrict__ Wkb, const float* __restrict__ bk,
    const bf16_t* __restrict__ XTc, const bf16_t* __restrict__ XTf,
    bf16_t* __restrict__ Qt, bf16_t* __restrict__ Kt)
{
    const int lane = threadIdx.x & 63, wave = threadIdx.x >> 6;
    const int g = lane >> 4, ln = lane & 15;
    const int b = blockIdx.y;
    const bool isK = wave >= 2;
    const int n_base = blockIdx.x * 32 + (wave & 1) * 16;
    const bf16_t* Wb = isK ? Wkb : Wqb;
    const float* bias = isK ? bk : bq;
    const float bscale = isK ? 1.0f : LOG2E;
    const bf16_t* XT = (isK ? XTf : XTc) + (size_t)b * N_PIX * CFEAT;
    bf16_t* Yt = (isK ? Kt : Qt) + (size_t)b * N_PIX * CKEY;

    // B-frags: B[k=s*32+g*8+j][ck=h*16+ln] = Wb[h*16+ln][s*32+g*8..]
    bf16x8 wf[8][2];
#pragma unroll
    for (int s = 0; s < 8; ++s)
#pragma unroll
        for (int h = 0; h < 2; ++h)
            wf[s][h] = *(const bf16x8*)&Wb[(size_t)(h * 16 + ln) * CFEAT + s * 32 + g * 8];

    f32x4 zero = {0.f, 0.f, 0.f, 0.f};
    f32x4 acc[2] = {zero, zero};
#pragma unroll
    for (int s = 0; s < 8; ++s) {
        const bf16x8 af = *(const bf16x8*)&XT[(size_t)(n_base + ln) * CFEAT + s * 32 + g * 8];
        acc[0] = mfma16(af, wf[s][0], acc[0]);
        acc[1] = mfma16(af, wf[s][1], acc[1]);
    }
#pragma unroll
    for (int h = 0; h < 2; ++h) {
        const float bv = bias[h * 16 + ln] * bscale;
#pragma unroll
        for (int r = 0; r < 4; ++r)
            Yt[(size_t)(n_base + g * 4 + r) * CKEY + h * 16 + ln] = (bf16_t)(acc[h][r] + bv);
    }
}

// ---------------------------------------------------------------------------
// projv: V[b][c][n] = Wv.feat + bv. A = Wvb rows (hoisted full K), B = XT rows.
// grid (N/64, C/64, B) = 1024; wave = 16 c x 64 n (4 n-tiles).
// ---------------------------------------------------------------------------
__global__ __launch_bounds__(256, 4) void projv_kernel(
    const bf16_t* __restrict__ Wvb, const float* __restrict__ bias,
    const bf16_t* __restrict__ XTf, bf16_t* __restrict__ V)
{
    const int lane = threadIdx.x & 63, wave = threadIdx.x >> 6;
    const int g = lane >> 4, ln = lane & 15;
    const int b = blockIdx.z;
    const int c_w = blockIdx.y * 64 + wave * 16;
    const int n0 = blockIdx.x * 64;
    const bf16_t* XT = XTf + (size_t)b * N_PIX * CFEAT;
    bf16_t* Vb = V + (size_t)b * CFEAT * N_PIX;

    bf16x8 af[8];
#pragma unroll
    for (int s = 0; s < 8; ++s)
        af[s] = *(const bf16x8*)&Wvb[(size_t)(c_w + ln) * CFEAT + s * 32 + g * 8];

    f32x4 zero = {0.f, 0.f, 0.f, 0.f};
#pragma unroll
    for (int nt = 0; nt < 4; ++nt) {
        bf16x8 bfr[8];
#pragma unroll
        for (int s = 0; s < 8; ++s)
            bfr[s] = *(const bf16x8*)&XT[(size_t)(n0 + nt * 16 + ln) * CFEAT + s * 32 + g * 8];
        f32x4 acc = zero;
#pragma unroll
        for (int s = 0; s < 8; ++s) acc = mfma16(af[s], bfr[s], acc);
#pragma unroll
        for (int r = 0; r < 4; ++r) {
            const int c = c_w + g * 4 + r;
            Vb[(size_t)c * N_PIX + n0 + nt * 16 + ln] = (bf16_t)(acc[r] + bias[c]);
        }
    }
}

// ---------------------------------------------------------------------------
// pv: out = gamma * softmax(QK^T).V / l + feat.  Max-free softmax with exp2
// (Q pre-scaled by log2e). S^T = K.Q^T so stats are per-lane scalars.
// Block = 64 i x 128 c; wave (iw,cw) = 32 i x 64 c. grid (2, N/64, B) = 512.
// V tile 128c x 64j staged via glds16, chunk-major [jc][c] (linear b128 reads),
// DOUBLE-buffered with glds issued AFTER the barrier (true 1-iter prefetch).
// P per-wave LDS, chunk-major [jc][i] (linear b128 reads). K direct global.
// ---------------------------------------------------------------------------
__global__ __launch_bounds__(256, 2) void pv_kernel(
    const bf16_t* __restrict__ Qt, const bf16_t* __restrict__ Kt,
    const bf16_t* __restrict__ V,
    const float* __restrict__ features, const float* __restrict__ gamma,
    float* __restrict__ out)
{
    __shared__ __attribute__((aligned(16))) bf16_t Vlds[2][128 * 64]; // slot=(jc*128+c)
    __shared__ __attribute__((aligned(16))) bf16_t Plds[4][8 * 32 * 8]; // slot=(jc*32+i)

    const int lane = threadIdx.x & 63, wave = threadIdx.x >> 6;
    const int g = lane >> 4, ln = lane & 15;
    const int iw = wave & 1, cw = wave >> 1;
    const int b = blockIdx.z;
    const int i_base = blockIdx.y * 64 + iw * 32;
    const int c_blk = blockIdx.x * 128;
    const int c_off = cw * 64;                      // wave's c within the tile

    const bf16_t* Qb = Qt + (size_t)b * N_PIX * CKEY;
    const bf16_t* Kb = Kt + (size_t)b * N_PIX * CKEY;
    const bf16_t* Vb = V + (size_t)b * CFEAT * N_PIX;
    bf16_t* Pw = &Plds[wave][0];

    // Q B-frags for S^T, one per i-half: B[k=ck][n=i] = Qt[i][ck]
    bf16x8 qf[2];
#pragma unroll
    for (int ih = 0; ih < 2; ++ih)
        qf[ih] = *(const bf16x8*)&Qb[(size_t)(i_base + ih * 16 + ln) * CKEY + g * 8];

    // staging map: thread t, call q: slot = q*256 + wave*64 + lane
    // slot -> (jc = slot>>7, c = slot&127); LDS dest base is wave-uniform.
    const bf16_t* vsrc[4];
#pragma unroll
    for (int q = 0; q < 4; ++q) {
        const int slot = q * 256 + wave * 64 + lane;
        vsrc[q] = Vb + (size_t)(c_blk + (slot & 127)) * N_PIX + (slot >> 7) * 8;
    }

    f32x4 zero = {0.f, 0.f, 0.f, 0.f};
    f32x4 acc[4][2];
#pragma unroll
    for (int ct = 0; ct < 4; ++ct) { acc[ct][0] = zero; acc[ct][1] = zero; }
    float ls[2] = {0.f, 0.f};

    // prologue: stage V(0) -> buf 0
#pragma unroll
    for (int q = 0; q < 4; ++q)
        glds16(vsrc[q], &Vlds[0][(q * 256 + wave * 64) * 8]);

    for (int n = 0; n < 64; ++n) {
        const int j0 = n * 64;
        // ---- S^T(n): A = K rows (16B global, L2-hot), 8 MFMAs ----
        bf16x8 kf[4];
#pragma unroll
        for (int jt = 0; jt < 4; ++jt)
            kf[jt] = *(const bf16x8*)&Kb[(size_t)(j0 + jt * 16 + ln) * CKEY + g * 8];
        f32x4 st[2][4];
#pragma unroll
        for (int ih = 0; ih < 2; ++ih)
#pragma unroll
            for (int jt = 0; jt < 4; ++jt) st[ih][jt] = mfma16(kf[jt], qf[ih], zero);

        // ---- exp2 -> P chunks [jc][i] (writer: jc=jt*2+(g>>1), pos=(g&1)*4+r) ----
#pragma unroll
        for (int ih = 0; ih < 2; ++ih)
#pragma unroll
            for (int jt = 0; jt < 4; ++jt) {
                bf16x4 p;
#pragma unroll
                for (int r = 0; r < 4; ++r) {
                    const float e = fexp2(st[ih][jt][r]);
                    ls[ih] += e;
                    p[r] = (bf16_t)e;
                }
                *(bf16x4*)&Pw[((jt * 2 + (g >> 1)) * 32 + ih * 16 + ln) * 8 + (g & 1) * 4] = p;
            }
        // ---- P B-frags: chunk (h*4+g, ih*16+ln) -> linear b128 ----
        bf16x8 pa[2][2];
#pragma unroll
        for (int h = 0; h < 2; ++h)
#pragma unroll
            for (int ih = 0; ih < 2; ++ih)
                pa[h][ih] = *(const bf16x8*)&Pw[((h * 4 + g) * 32 + ih * 16 + ln) * 8];

        // ---- barrier: drains V(n) DMA; then issue V(n+1) (true prefetch) ----
        __syncthreads();
        const int jn = (j0 + 64) & (N_PIX - 1);   // wrap on last iter: unused
        const int bn = (n + 1) & 1;
#pragma unroll
        for (int q = 0; q < 4; ++q)
            glds16(vsrc[q] + jn, &Vlds[bn][(q * 256 + wave * 64) * 8]);

        // ---- PV(n): V A-frags chunk (h*4+g, c_off+ct*16+ln) -> linear b128 ----
        const bf16_t* Vt = &Vlds[n & 1][0];
#pragma unroll
        for (int ct = 0; ct < 4; ++ct) {
            bf16x8 va[2];
#pragma unroll
            for (int h = 0; h < 2; ++h)
                va[h] = *(const bf16x8*)&Vt[((h * 4 + g) * 128 + c_off + ct * 16 + ln) * 8];
#pragma unroll
            for (int h = 0; h < 2; ++h)
#pragma unroll
                for (int ih = 0; ih < 2; ++ih)
                    acc[ct][ih] = mfma16(va[h], pa[h][ih], acc[ct][ih]);
        }
    }

    const float gam = gamma[0];
    float s_lane[2];
#pragma unroll
    for (int ih = 0; ih < 2; ++ih) {
        ls[ih] += __shfl_xor(ls[ih], 16);
        ls[ih] += __shfl_xor(ls[ih], 32);
        s_lane[ih] = gam / ls[ih];
    }
#pragma unroll
    for (int ct = 0; ct < 4; ++ct)
#pragma unroll
        for (int ih = 0; ih < 2; ++ih)
#pragma unroll
            for (int r = 0; r < 4; ++r) {
                const int c = c_blk + c_off + ct * 16 + g * 4 + r;  // D row
                const int i = i_base + ih * 16 + ln;                // D col
                const size_t idx = ((size_t)b * CFEAT + c) * N_PIX + i;
                out[idx] = s_lane[ih] * acc[ct][ih][r] + features[idx];
            }
}

// ---------------------------------------------------------------------------
extern "C" void kernel_launch(void* const* d_in, const int* in_sizes, int n_in,
                              void* d_out, int out_size, void* d_ws, size_t ws_size,
                              hipStream_t stream) {
    const float* features   = (const float*)d_in[0];
    const float* conditions = (const float*)d_in[1];
    const float* Wq  = (const float*)d_in[2];
    const float* bq  = (const float*)d_in[3];
    const float* Wk  = (const float*)d_in[4];
    const float* bk  = (const float*)d_in[5];
    const float* Wv  = (const float*)d_in[6];
    const float* bv  = (const float*)d_in[7];
    const float* gam = (const float*)d_in[8];
    float* out = (float*)d_out;

    // ws (bf16): Qt 1MB | Kt 1MB | V 8MB | XTf 8MB | XTc 8MB | Wqb,Wkb,Wvb 160KB
    bf16_t* Qt  = (bf16_t*)d_ws;
    bf16_t* Kt  = Qt  + (size_t)NBATCH * N_PIX * CKEY;
    bf16_t* Vw  = Kt  + (size_t)NBATCH * N_PIX * CKEY;
    bf16_t* XTf = Vw  + (size_t)NBATCH * CFEAT * N_PIX;
    bf16_t* XTc = XTf + (size_t)NBATCH * N_PIX * CFEAT;
    bf16_t* Wqb = XTc + (size_t)NBATCH * N_PIX * CFEAT;
    bf16_t* Wkb = Wqb + CKEY * CFEAT;
    bf16_t* Wvb = Wkb + CKEY * CFEAT;

    wcvt_kernel<<<dim3(320), 256, 0, stream>>>(Wq, Wk, Wv, Wqb, Wkb, Wvb);
    transpose_kernel<<<dim3(N_PIX / 64, CFEAT / 64, 2 * NBATCH), 256, 0, stream>>>(
        features, conditions, XTf, XTc);
    projqk_kernel<<<dim3(N_PIX / 32, NBATCH), 256, 0, stream>>>(
        Wqb, bq, Wkb, bk, XTc, XTf, Qt, Kt);
    projv_kernel<<<dim3(N_PIX / 64, CFEAT / 64, NBATCH), 256, 0, stream>>>(
        Wvb, bv, XTf, Vw);
    pv_kernel<<<dim3(2, N_PIX / 64, NBATCH), 256, 0, stream>>>(
        Qt, Kt, Vw, features, gam, out);
}